// Round 1
// 451.859 us; speedup vs baseline: 1.0592x; 1.0592x over previous
//
#include <hip/hip_runtime.h>
#include <hip/hip_bf16.h>
#include <math.h>

// Problem constants
#define VV 50257
#define EE 1024
#define HH 1024
#define SS 2048
#define VS (VV + SS)   // 52305

#define NSCB 2048      // k_scores block count (ms/ls partial count)

// Workspace layout (float offsets)
#define OFF_LOGA   0                    // attn logits [2048]
#define OFF_CTX    2048                 // ctx accumulator [2048] (zeroed in k_front)
#define OFF_SEL    4096                 // selective ctx accumulator [2048]
#define OFF_LSTMIN 6144                 // lstm_in [3072] = [xe, selective, attentive]
#define OFF_GATES  9216                 // gates [4096]
#define OFF_LOG    13312                // score logits [52305]
#define OFF_MS     65664                // per-scores-block softmax max [2048]
#define OFF_LS     67712                // per-scores-block softmax sum [2048]
#define OFF_T0     69760                // Wc GEMM partial, K-half 0: [2048*1024] fp32
#define OFF_T1     (69760 + 2048*1024)  // K-half 1 partial
#define OFF_ENCB   (OFF_T1 + 2048*1024) // enc as bf16 [2048*2048 ushort] (= 2M floats)
#define OFF_WCB    (OFF_ENCB + 2048*1024) // Wc_W as bf16 [1024*2048 ushort] (= 1M floats)

typedef __attribute__((ext_vector_type(8))) short bf16x8;
typedef __attribute__((ext_vector_type(8))) unsigned short u16x8;
typedef __attribute__((ext_vector_type(4))) float f32x4;

__device__ inline float wave_reduce(float v) {
    #pragma unroll
    for (int off = 32; off > 0; off >>= 1) v += __shfl_down(v, off, 64);
    return v;
}

__device__ inline unsigned short f2bf(float f) {
    unsigned int u = __builtin_bit_cast(unsigned int, f);
    u += 0x7FFFu + ((u >> 16) & 1u);
    return (unsigned short)(u >> 16);
}

// ---- 1. k_front (fused): blocks 0..511 attn logits (one wave/row);
//         512..1023 enc->bf16; 1024..1279 Wc_W->bf16; 1280 zero ctx/sel; 1281 copy xe
__global__ __launch_bounds__(256) void k_front(
        const float* __restrict__ x, const float* __restrict__ h0,
        const float* __restrict__ attn_W, const float* __restrict__ attn_b,
        float* __restrict__ loga,
        const float* __restrict__ enc, const float* __restrict__ Wc_W,
        unsigned short* __restrict__ encb, unsigned short* __restrict__ Wcb,
        float* __restrict__ ctxsel, float* __restrict__ lstm_in) {
    int bx = blockIdx.x, tid = threadIdx.x;
    if (bx < 512) {
        // attn logits[s] = dot(concat(x,h0), attn_W[s]) + attn_b[s]
        int wave = (bx * 256 + tid) >> 6;     // 0..2047
        int lane = tid & 63;
        const float4* rp = (const float4*)(attn_W + (size_t)wave * 2048);
        float acc = 0.f;
        #pragma unroll
        for (int k = 0; k < 8; ++k) {
            int idx = lane + 64 * k;
            float4 w = rp[idx];
            int j = idx * 4;
            const float* cat = (j < 1024) ? (x + j) : (h0 + (j - 1024));
            acc += w.x * cat[0] + w.y * cat[1] + w.z * cat[2] + w.w * cat[3];
        }
        acc = wave_reduce(acc);
        if (lane == 0) loga[wave] = acc + attn_b[wave];
        return;
    }
    if (bx < 1280) {
        // f32 -> bf16 conversion, 8192 elems/block
        bool isenc = bx < 1024;
        int b = isenc ? bx - 512 : bx - 1024;
        const float* src = isenc ? enc : Wc_W;
        unsigned short* dst = isenc ? encb : Wcb;
        size_t base = (size_t)b * 8192;
        #pragma unroll
        for (int p = 0; p < 8; ++p) {
            size_t idx = base + p * 1024 + tid * 4;
            float4 v = *(const float4*)(src + idx);
            ushort4 o = { f2bf(v.x), f2bf(v.y), f2bf(v.z), f2bf(v.w) };
            *(ushort4*)(dst + idx) = o;
        }
        return;
    }
    if (bx == 1280) {
        for (int j = tid; j < 4096; j += 256) ctxsel[j] = 0.f;
        return;
    }
    for (int j = tid; j < EE; j += 256) lstm_in[j] = x[j];
}

// ---- 2. k_ctx (fused softmax+rho prep, redundant per block):
//   each block recomputes global softmax scalars (m, 1/sum, 1/rhosum) from logits,
//   then accumulates ctx/sel for its 64-row slice with atomics. grid (2, 32).
__global__ __launch_bounds__(256) void k_ctx(
        const float* __restrict__ enc, const float* __restrict__ logits,
        const int* __restrict__ sentence, const float* __restrict__ prev_probs,
        const int* __restrict__ prev_word,
        float* __restrict__ ctx, float* __restrict__ selctx) {
    __shared__ float red[256];
    __shared__ float aw[64], rh[64];
    int tid = threadIdx.x;
    // global max of attn logits
    float m = -1e30f;
    for (int s = tid; s < SS; s += 256) m = fmaxf(m, logits[s]);
    red[tid] = m; __syncthreads();
    for (int o = 128; o > 0; o >>= 1) { if (tid < o) red[tid] = fmaxf(red[tid], red[tid + o]); __syncthreads(); }
    m = red[0]; __syncthreads();
    // sum of exp
    float sum = 0.f;
    for (int s = tid; s < SS; s += 256) sum += __expf(logits[s] - m);
    red[tid] = sum; __syncthreads();
    for (int o = 128; o > 0; o >>= 1) { if (tid < o) red[tid] += red[tid + o]; __syncthreads(); }
    float inv = 1.f / red[0]; __syncthreads();
    // rho sum
    int pw = prev_word[0];
    float rsum = 0.f;
    for (int s = tid; s < SS; s += 256) rsum += (sentence[s] == pw) ? prev_probs[VV + s] : 0.f;
    red[tid] = rsum; __syncthreads();
    for (int o = 128; o > 0; o >>= 1) { if (tid < o) red[tid] += red[tid + o]; __syncthreads(); }
    float rinv = 1.f / (red[0] + 1e-9f); __syncthreads();
    // local 64-row weights
    int s0 = blockIdx.y * 64;
    if (tid < 64) {
        int s = s0 + tid;
        aw[tid] = __expf(logits[s] - m) * inv;
        rh[tid] = ((sentence[s] == pw) ? prev_probs[VV + s] : 0.f) * rinv;
    }
    __syncthreads();
    // accumulate
    int col4 = blockIdx.x * 256 + tid;   // 0..511 (512 float4 cols)
    float4 a = {0.f, 0.f, 0.f, 0.f}, r = {0.f, 0.f, 0.f, 0.f};
    const float4* p = (const float4*)enc + (size_t)s0 * 512 + col4;
    #pragma unroll 4
    for (int i = 0; i < 64; ++i) {
        float4 v = p[(size_t)i * 512];
        float w = aw[i], q = rh[i];
        a.x += w * v.x; a.y += w * v.y; a.z += w * v.z; a.w += w * v.w;
        r.x += q * v.x; r.y += q * v.y; r.z += q * v.z; r.w += q * v.w;
    }
    int c = col4 * 4;
    atomicAdd(&ctx[c], a.x); atomicAdd(&ctx[c+1], a.y); atomicAdd(&ctx[c+2], a.z); atomicAdd(&ctx[c+3], a.w);
    atomicAdd(&selctx[c], r.x); atomicAdd(&selctx[c+1], r.y); atomicAdd(&selctx[c+2], r.z); atomicAdd(&selctx[c+3], r.w);
}

// ---- 3. k_comb: attentive (comb_W) + selective (Ws_W) matvecs -> lstm_in, one wave/row
__global__ __launch_bounds__(256) void k_comb(
        const float* __restrict__ ctx, const float* __restrict__ selctx,
        const float* __restrict__ comb_W, const float* __restrict__ comb_b,
        const float* __restrict__ Ws_W, const float* __restrict__ Ws_b,
        float* __restrict__ lstm_in) {
    int wave = (blockIdx.x * blockDim.x + threadIdx.x) >> 6;
    int lane = threadIdx.x & 63;
    bool sel = wave >= 1024;
    int i = sel ? wave - 1024 : wave;
    const float4* rp = (const float4*)((sel ? Ws_W : comb_W) + (size_t)i * 2048);
    const float4* vp = (const float4*)(sel ? selctx : ctx);
    float acc = 0.f;
    #pragma unroll
    for (int k = 0; k < 8; ++k) {
        int idx = lane + 64 * k;
        float4 w = rp[idx]; float4 v = vp[idx];
        acc += w.x * v.x + w.y * v.y + w.z * v.z + w.w * v.w;
    }
    acc = wave_reduce(acc);
    if (lane == 0) lstm_in[sel ? (1024 + i) : (2048 + i)] = acc + (sel ? Ws_b[i] : comb_b[i]);
}

// ---- 4. k_gates_gemm (fused): blocks 0..1023 LSTM gate matvecs (one wave/row);
//        blocks 1024..1279 Wc GEMM (bf16 inputs, 128x128 tile, split-K=2)
__global__ __launch_bounds__(256) void k_gates_gemm(
        const float* __restrict__ lstm_in, const float* __restrict__ h0,
        const float* __restrict__ W_ih, const float* __restrict__ W_hh,
        const float* __restrict__ b_ih, const float* __restrict__ b_hh,
        float* __restrict__ gates,
        const unsigned short* __restrict__ Ab,   // enc bf16 2048x2048
        const unsigned short* __restrict__ Bb,   // Wc_W bf16 1024x2048
        float* __restrict__ T0, float* __restrict__ T1) {
    __shared__ __attribute__((aligned(16))) unsigned short As[128 * 32];
    __shared__ __attribute__((aligned(16))) unsigned short Bs[128 * 32];
    int tid = threadIdx.x;
    if (blockIdx.x < 1024) {
        // ---- gates path: gates[r] = lstm_in.W_ih[r] + h0.W_hh[r] + b_ih + b_hh
        int wave = (blockIdx.x * 256 + tid) >> 6;  // 0..4095
        int lane = tid & 63;
        const float4* rp = (const float4*)(W_ih + (size_t)wave * 3072);
        const float4* vp = (const float4*)lstm_in;
        float acc = 0.f;
        #pragma unroll
        for (int k = 0; k < 12; ++k) {
            int idx = lane + 64 * k;
            float4 w = rp[idx]; float4 v = vp[idx];
            acc += w.x * v.x + w.y * v.y + w.z * v.z + w.w * v.w;
        }
        const float4* hp = (const float4*)(W_hh + (size_t)wave * 1024);
        const float4* h4 = (const float4*)h0;
        #pragma unroll
        for (int k = 0; k < 4; ++k) {
            int idx = lane + 64 * k;
            float4 w = hp[idx]; float4 v = h4[idx];
            acc += w.x * v.x + w.y * v.y + w.z * v.z + w.w * v.w;
        }
        acc = wave_reduce(acc);
        if (lane == 0) gates[wave] = acc + b_ih[wave] + b_hh[wave];
        return;
    }
    // ---- GEMM path: T{s} = enc[:, sK*1024:+1024] @ Wc_W[:, sK*1024:+1024]^T
    int gg = blockIdx.x - 1024;          // 0..255
    int sK = gg >> 7;                    // split-K index 0/1
    int rem = gg & 127;
    int mbase = (rem >> 3) * 128;        // 16 m-blocks
    int nbase = (rem & 7) * 128;         // 8 n-blocks
    float* C = sK ? T1 : T0;
    int lane = tid & 63;
    int wid = tid >> 6;
    int wm = (wid >> 1) * 64;
    int wn = (wid & 1) * 64;
    int lrow = lane & 15;
    int lk = (lane >> 4) * 8;
    f32x4 acc[4][4] = {};
    int kbeg = sK * 1024;
    for (int k0 = kbeg; k0 < kbeg + 1024; k0 += 32) {
        // stage 128x32 bf16 tiles: 2x 16B chunks per thread per operand
        #pragma unroll
        for (int p = 0; p < 2; ++p) {
            int fi = p * 256 + tid;      // 0..511
            int row = fi >> 2;           // 0..127
            int c8 = fi & 3;             // 8-bf16 chunk within the 32-wide slice
            *(u16x8*)(As + row * 32 + c8 * 8) =
                *(const u16x8*)(Ab + (size_t)(mbase + row) * 2048 + k0 + c8 * 8);
            *(u16x8*)(Bs + row * 32 + c8 * 8) =
                *(const u16x8*)(Bb + (size_t)(nbase + row) * 2048 + k0 + c8 * 8);
        }
        __syncthreads();
        bf16x8 af[4], bfr[4];
        #pragma unroll
        for (int t = 0; t < 4; ++t) {
            af[t]  = *(const bf16x8*)(As + (wm + t * 16 + lrow) * 32 + lk);
            bfr[t] = *(const bf16x8*)(Bs + (wn + t * 16 + lrow) * 32 + lk);
        }
        #pragma unroll
        for (int mt = 0; mt < 4; ++mt)
            #pragma unroll
            for (int nt = 0; nt < 4; ++nt)
                acc[mt][nt] = __builtin_amdgcn_mfma_f32_16x16x32_bf16(af[mt], bfr[nt], acc[mt][nt], 0, 0, 0);
        __syncthreads();
    }
    int crow0 = (lane >> 4) * 4;
    int ccol = lane & 15;
    #pragma unroll
    for (int mt = 0; mt < 4; ++mt)
        #pragma unroll
        for (int nt = 0; nt < 4; ++nt) {
            int col = nbase + wn + nt * 16 + ccol;
            #pragma unroll
            for (int r = 0; r < 4; ++r) {
                int row = mbase + wm + mt * 16 + crow0 + r;
                C[(size_t)row * 1024 + col] = acc[mt][nt][r];
            }
        }
}

// ---- 5. k_scores (fused LSTM pointwise + scores + per-block online softmax):
//   each block recomputes h1 into LDS (block 0 also writes h1/c1 to d_out),
//   then persistent wave-per-row over 52305 logits, tracking online (m,l).
__global__ __launch_bounds__(256) void k_scores(
        const float* __restrict__ gates, const float* __restrict__ c0,
        const float* __restrict__ Wo_W, const float* __restrict__ Wo_b,
        const float* __restrict__ T0, const float* __restrict__ T1,
        const float* __restrict__ Wc_b,
        float* __restrict__ logits, float* __restrict__ out,
        float* __restrict__ ms, float* __restrict__ ls) {
    __shared__ float h1s[1024];
    __shared__ float wm_s[4], wl_s[4];
    int tid = threadIdx.x, bid = blockIdx.x;
    #pragma unroll
    for (int kk = 0; kk < 4; ++kk) {
        int j = tid + 256 * kk;
        float ig = gates[j], fg = gates[1024 + j], gg = gates[2048 + j], og = gates[3072 + j];
        float si = 1.f / (1.f + __expf(-ig));
        float sf = 1.f / (1.f + __expf(-fg));
        float so = 1.f / (1.f + __expf(-og));
        float c1 = sf * c0[j] + si * tanhf(gg);
        float h1 = so * tanhf(c1);
        h1s[j] = h1;
        if (bid == 0) { out[VS + j] = h1; out[VS + 1024 + j] = c1; }
    }
    __syncthreads();
    int lane = tid & 63, wid = tid >> 6;
    int gw = bid * 4 + wid;              // global wave 0..8191
    float m = -1e30f, l = 0.f;
    const float4* hp = (const float4*)h1s;
    for (int v = gw; v < VS; v += NSCB * 4) {
        float acc = 0.f;
        if (v < VV) {
            const float4* rp = (const float4*)(Wo_W + (size_t)v * 1024);
            #pragma unroll
            for (int k = 0; k < 4; ++k) {
                int idx = lane + 64 * k;
                float4 w = rp[idx]; float4 hv = hp[idx];
                acc += w.x * hv.x + w.y * hv.y + w.z * hv.z + w.w * hv.w;
            }
        } else {
            int r = v - VV;
            const float4* p0 = (const float4*)(T0 + (size_t)r * 1024);
            const float4* p1 = (const float4*)(T1 + (size_t)r * 1024);
            const float4* bp = (const float4*)Wc_b;
            #pragma unroll
            for (int k = 0; k < 4; ++k) {
                int idx = lane + 64 * k;
                float4 a0 = p0[idx], a1 = p1[idx], bb = bp[idx], hv = hp[idx];
                acc += tanhf(a0.x + a1.x + bb.x) * hv.x + tanhf(a0.y + a1.y + bb.y) * hv.y
                     + tanhf(a0.z + a1.z + bb.z) * hv.z + tanhf(a0.w + a1.w + bb.w) * hv.w;
            }
        }
        acc = wave_reduce(acc);
        if (lane == 0) {
            float lg = acc + (v < VV ? Wo_b[v] : 0.f);
            logits[v] = lg;
            float nm = fmaxf(m, lg);
            l = l * __expf(m - nm) + __expf(lg - nm);
            m = nm;
        }
    }
    if (lane == 0) { wm_s[wid] = m; wl_s[wid] = l; }
    __syncthreads();
    if (tid == 0) {
        float M = wm_s[0], L = wl_s[0];
        #pragma unroll
        for (int w = 1; w < 4; ++w) {
            float nm = fmaxf(M, wm_s[w]);
            L = L * __expf(M - nm) + wl_s[w] * __expf(wm_s[w] - nm);
            M = nm;
        }
        ms[bid] = M; ls[bid] = L;
    }
}

// ---- 6. k_smfinal (fused merge + write): each block redundantly merges the 2048
//   per-block (m,l) partials (L2-resident), then writes its slice of probs.
__global__ __launch_bounds__(256) void k_smfinal(
        const float* __restrict__ ms, const float* __restrict__ ls,
        const float* __restrict__ logits, float* __restrict__ out) {
    __shared__ float rm[256], rl[256];
    int tid = threadIdx.x;
    float m = -1e30f, l = 0.f;
    for (int i = tid; i < NSCB; i += 256) {
        float bm = ms[i], bl = ls[i];
        float nm = fmaxf(m, bm);
        l = l * __expf(m - nm) + bl * __expf(bm - nm);
        m = nm;
    }
    rm[tid] = m; rl[tid] = l; __syncthreads();
    for (int o = 128; o > 0; o >>= 1) {
        if (tid < o) {
            float m2 = rm[tid + o], l2 = rl[tid + o];
            float nm = fmaxf(rm[tid], m2);
            rl[tid] = rl[tid] * __expf(rm[tid] - nm) + l2 * __expf(m2 - nm);
            rm[tid] = nm;
        }
        __syncthreads();
    }
    float M = rm[0], Linv = 1.f / rl[0];
    for (int v = blockIdx.x * 256 + tid; v < VS; v += 128 * 256)
        out[v] = __expf(logits[v] - M) * Linv;
}

extern "C" void kernel_launch(void* const* d_in, const int* in_sizes, int n_in,
                              void* d_out, int out_size, void* d_ws, size_t ws_size,
                              hipStream_t stream) {
    (void)in_sizes; (void)n_in; (void)out_size; (void)ws_size;
    const float* x          = (const float*)d_in[0];
    const float* enc        = (const float*)d_in[1];
    const int*   sentence   = (const int*)d_in[2];
    const float* prev_probs = (const float*)d_in[3];
    const float* h0         = (const float*)d_in[4];
    const float* c0         = (const float*)d_in[5];
    const float* attn_W     = (const float*)d_in[6];
    const float* attn_b     = (const float*)d_in[7];
    const float* comb_W     = (const float*)d_in[8];
    const float* comb_b     = (const float*)d_in[9];
    const float* Ws_W       = (const float*)d_in[10];
    const float* Ws_b       = (const float*)d_in[11];
    const float* Wo_W       = (const float*)d_in[12];
    const float* Wo_b       = (const float*)d_in[13];
    const float* Wc_W       = (const float*)d_in[14];
    const float* Wc_b       = (const float*)d_in[15];
    const float* W_ih       = (const float*)d_in[16];
    const float* W_hh       = (const float*)d_in[17];
    const float* b_ih       = (const float*)d_in[18];
    const float* b_hh       = (const float*)d_in[19];
    const int*   prev_word  = (const int*)d_in[20];
    float* ws  = (float*)d_ws;
    float* out = (float*)d_out;
    unsigned short* encb = (unsigned short*)(ws + OFF_ENCB);
    unsigned short* Wcb  = (unsigned short*)(ws + OFF_WCB);

    k_front<<<1282, 256, 0, stream>>>(x, h0, attn_W, attn_b, ws + OFF_LOGA,
                                      enc, Wc_W, encb, Wcb,
                                      ws + OFF_CTX, ws + OFF_LSTMIN);
    k_ctx<<<dim3(2, 32), 256, 0, stream>>>(enc, ws + OFF_LOGA, sentence, prev_probs,
                                           prev_word, ws + OFF_CTX, ws + OFF_SEL);
    k_comb<<<512, 256, 0, stream>>>(ws + OFF_CTX, ws + OFF_SEL, comb_W, comb_b,
                                    Ws_W, Ws_b, ws + OFF_LSTMIN);
    k_gates_gemm<<<1280, 256, 0, stream>>>(ws + OFF_LSTMIN, h0, W_ih, W_hh, b_ih, b_hh,
                                           ws + OFF_GATES, encb, Wcb,
                                           ws + OFF_T0, ws + OFF_T1);
    k_scores<<<NSCB, 256, 0, stream>>>(ws + OFF_GATES, c0, Wo_W, Wo_b,
                                       ws + OFF_T0, ws + OFF_T1, Wc_b,
                                       ws + OFF_LOG, out, ws + OFF_MS, ws + OFF_LS);
    k_smfinal<<<128, 256, 0, stream>>>(ws + OFF_MS, ws + OFF_LS, ws + OFF_LOG, out);
}

// Round 3
// 446.081 us; speedup vs baseline: 1.0729x; 1.0130x over previous
//
#include <hip/hip_runtime.h>
#include <hip/hip_bf16.h>
#include <math.h>

// Problem constants
#define VV 50257
#define EE 1024
#define HH 1024
#define SS 2048
#define VS (VV + SS)   // 52305

#define NWOB 1792               // Wo-scoring blocks in k_scores
#define NWOW (NWOB * 4)         // Wo waves

// Workspace layout (float offsets)
#define OFF_LOGA   0                    // attn logits [2048]
#define OFF_CTX    2048                 // ctx accumulator [2048]      (zeroed in k_front)
#define OFF_SEL    4096                 // selective ctx accum [2048]  (zeroed in k_front)
#define OFF_SCOREC 6144                 // score_c accumulator [2048]  (zeroed in k_front)
#define OFF_LSTMIN 8192                 // lstm_in [3072] = [xe, selective, attentive]
#define OFF_GATES  11264                // gates [4096]
#define OFF_LOG    15360                // Wo score logits [52305] -> ends 67665
#define OFF_MS     67712                // per-Wo-block softmax max [1792]
#define OFF_LS     69504                // per-Wo-block softmax sum [1792]
#define OFF_ENCB   71296                // enc bf16 [2048*2048 ushort] (2,097,152 floats)
#define OFF_WCB    (71296 + 2097152)    // Wc_W bf16 [1024*2048 ushort] (1,048,576 floats)

typedef __attribute__((ext_vector_type(8))) short bf16x8;
typedef __attribute__((ext_vector_type(8))) unsigned short u16x8;
typedef __attribute__((ext_vector_type(4))) float f32x4;

__device__ inline float wave_reduce(float v) {
    #pragma unroll
    for (int off = 32; off > 0; off >>= 1) v += __shfl_down(v, off, 64);
    return v;
}

__device__ inline unsigned short f2bf(float f) {
    unsigned int u = __builtin_bit_cast(unsigned int, f);
    u += 0x7FFFu + ((u >> 16) & 1u);
    return (unsigned short)(u >> 16);
}

// ---- 1. k_front: blocks 0..511 attn logits; 512..1279 f32->bf16 convert;
//         1280 zero ctx/sel/scorec; 1281 copy xe
__global__ __launch_bounds__(256) void k_front(
        const float* __restrict__ x, const float* __restrict__ h0,
        const float* __restrict__ attn_W, const float* __restrict__ attn_b,
        float* __restrict__ loga,
        const float* __restrict__ enc, const float* __restrict__ Wc_W,
        unsigned short* __restrict__ encb, unsigned short* __restrict__ Wcb,
        float* __restrict__ zbase, float* __restrict__ lstm_in) {
    int bx = blockIdx.x, tid = threadIdx.x;
    if (bx < 512) {
        int wave = (bx * 256 + tid) >> 6;     // 0..2047
        int lane = tid & 63;
        const float4* rp = (const float4*)(attn_W + (size_t)wave * 2048);
        float acc = 0.f;
        #pragma unroll
        for (int k = 0; k < 8; ++k) {
            int idx = lane + 64 * k;
            float4 w = rp[idx];
            int j = idx * 4;
            const float* cat = (j < 1024) ? (x + j) : (h0 + (j - 1024));
            acc += w.x * cat[0] + w.y * cat[1] + w.z * cat[2] + w.w * cat[3];
        }
        acc = wave_reduce(acc);
        if (lane == 0) loga[wave] = acc + attn_b[wave];
        return;
    }
    if (bx < 1280) {
        // f32 -> bf16 conversion, 8192 elems/block
        bool isenc = bx < 1024;
        int b = isenc ? bx - 512 : bx - 1024;
        const float* src = isenc ? enc : Wc_W;
        unsigned short* dst = isenc ? encb : Wcb;
        size_t base = (size_t)b * 8192;
        #pragma unroll
        for (int p = 0; p < 8; ++p) {
            size_t idx = base + p * 1024 + tid * 4;
            float4 v = *(const float4*)(src + idx);
            ushort4 o = { f2bf(v.x), f2bf(v.y), f2bf(v.z), f2bf(v.w) };
            *(ushort4*)(dst + idx) = o;
        }
        return;
    }
    if (bx == 1280) {
        for (int j = tid; j < 6144; j += 256) zbase[j] = 0.f;  // ctx+sel+scorec
        return;
    }
    for (int j = tid; j < EE; j += 256) lstm_in[j] = x[j];
}

// ---- 2. k_ctx: redundant per-block softmax scalars, then 64-row slice accumulate
__global__ __launch_bounds__(256) void k_ctx(
        const float* __restrict__ enc, const float* __restrict__ logits,
        const int* __restrict__ sentence, const float* __restrict__ prev_probs,
        const int* __restrict__ prev_word,
        float* __restrict__ ctx, float* __restrict__ selctx) {
    __shared__ float red[256];
    __shared__ float aw[64], rh[64];
    int tid = threadIdx.x;
    float m = -1e30f;
    for (int s = tid; s < SS; s += 256) m = fmaxf(m, logits[s]);
    red[tid] = m; __syncthreads();
    for (int o = 128; o > 0; o >>= 1) { if (tid < o) red[tid] = fmaxf(red[tid], red[tid + o]); __syncthreads(); }
    m = red[0]; __syncthreads();
    float sum = 0.f;
    for (int s = tid; s < SS; s += 256) sum += __expf(logits[s] - m);
    red[tid] = sum; __syncthreads();
    for (int o = 128; o > 0; o >>= 1) { if (tid < o) red[tid] += red[tid + o]; __syncthreads(); }
    float inv = 1.f / red[0]; __syncthreads();
    int pw = prev_word[0];
    float rsum = 0.f;
    for (int s = tid; s < SS; s += 256) rsum += (sentence[s] == pw) ? prev_probs[VV + s] : 0.f;
    red[tid] = rsum; __syncthreads();
    for (int o = 128; o > 0; o >>= 1) { if (tid < o) red[tid] += red[tid + o]; __syncthreads(); }
    float rinv = 1.f / (red[0] + 1e-9f); __syncthreads();
    int s0 = blockIdx.y * 64;
    if (tid < 64) {
        int s = s0 + tid;
        aw[tid] = __expf(logits[s] - m) * inv;
        rh[tid] = ((sentence[s] == pw) ? prev_probs[VV + s] : 0.f) * rinv;
    }
    __syncthreads();
    int col4 = blockIdx.x * 256 + tid;
    float4 a = {0.f,0.f,0.f,0.f}, r = {0.f,0.f,0.f,0.f};
    const float4* p = (const float4*)enc + (size_t)s0 * 512 + col4;
    #pragma unroll 4
    for (int i = 0; i < 64; ++i) {
        float4 v = p[(size_t)i * 512];
        float w = aw[i], q = rh[i];
        a.x += w*v.x; a.y += w*v.y; a.z += w*v.z; a.w += w*v.w;
        r.x += q*v.x; r.y += q*v.y; r.z += q*v.z; r.w += q*v.w;
    }
    int c = col4 * 4;
    atomicAdd(&ctx[c],   a.x); atomicAdd(&ctx[c+1],   a.y); atomicAdd(&ctx[c+2],   a.z); atomicAdd(&ctx[c+3],   a.w);
    atomicAdd(&selctx[c],r.x); atomicAdd(&selctx[c+1],r.y); atomicAdd(&selctx[c+2],r.z); atomicAdd(&selctx[c+3],r.w);
}

// ---- 3. k_comb: attentive (comb_W) + selective (Ws_W) matvecs -> lstm_in
__global__ __launch_bounds__(256) void k_comb(
        const float* __restrict__ ctx, const float* __restrict__ selctx,
        const float* __restrict__ comb_W, const float* __restrict__ comb_b,
        const float* __restrict__ Ws_W, const float* __restrict__ Ws_b,
        float* __restrict__ lstm_in) {
    int wave = (blockIdx.x * blockDim.x + threadIdx.x) >> 6;
    int lane = threadIdx.x & 63;
    bool sel = wave >= 1024;
    int i = sel ? wave - 1024 : wave;
    const float4* rp = (const float4*)((sel ? Ws_W : comb_W) + (size_t)i * 2048);
    const float4* vp = (const float4*)(sel ? selctx : ctx);
    float acc = 0.f;
    #pragma unroll
    for (int k = 0; k < 8; ++k) {
        int idx = lane + 64 * k;
        float4 w = rp[idx]; float4 v = vp[idx];
        acc += w.x*v.x + w.y*v.y + w.z*v.z + w.w*v.w;
    }
    acc = wave_reduce(acc);
    if (lane == 0) lstm_in[sel ? (1024 + i) : (2048 + i)] = acc + (sel ? Ws_b[i] : comb_b[i]);
}

// ---- 4. k_gates: gates[r] = lstm_in.W_ih[r] + h0.W_hh[r] + b_ih + b_hh
__global__ __launch_bounds__(256) void k_gates(
        const float* __restrict__ lstm_in, const float* __restrict__ h0,
        const float* __restrict__ W_ih, const float* __restrict__ W_hh,
        const float* __restrict__ b_ih, const float* __restrict__ b_hh,
        float* __restrict__ gates) {
    int wave = (blockIdx.x * 256 + threadIdx.x) >> 6;  // 0..4095
    int lane = threadIdx.x & 63;
    const float4* rp = (const float4*)(W_ih + (size_t)wave * 3072);
    const float4* vp = (const float4*)lstm_in;
    float acc = 0.f;
    #pragma unroll
    for (int k = 0; k < 12; ++k) {
        int idx = lane + 64 * k;
        float4 w = rp[idx]; float4 v = vp[idx];
        acc += w.x*v.x + w.y*v.y + w.z*v.z + w.w*v.w;
    }
    const float4* hp = (const float4*)(W_hh + (size_t)wave * 1024);
    const float4* h4 = (const float4*)h0;
    #pragma unroll
    for (int k = 0; k < 4; ++k) {
        int idx = lane + 64 * k;
        float4 w = hp[idx]; float4 v = h4[idx];
        acc += w.x*v.x + w.y*v.y + w.z*v.z + w.w*v.w;
    }
    acc = wave_reduce(acc);
    if (lane == 0) gates[wave] = acc + b_ih[wave] + b_hh[wave];
}

// ---- 5. k_scores: every block recomputes h1 (from gates) into LDS.
//   blocks 0..255: Wc GEMM 64x128 K-complete tiles (bf16 MFMA) with fused
//                  tanh(.+Wc_b)*h1 epilogue -> atomicAdd into scorec[2048].
//   blocks 256..2047: Wo matvec rows + online per-block (m,l) into ms/ls.
__global__ __launch_bounds__(256) void k_scores(
        const float* __restrict__ gates, const float* __restrict__ c0,
        const float* __restrict__ Wo_W, const float* __restrict__ Wo_b,
        const float* __restrict__ Wc_b,
        const unsigned short* __restrict__ encb, const unsigned short* __restrict__ Wcb,
        float* __restrict__ logits, float* __restrict__ out,
        float* __restrict__ ms, float* __restrict__ ls,
        float* __restrict__ scorec) {
    __shared__ __attribute__((aligned(16))) unsigned short As[64 * 32];
    __shared__ __attribute__((aligned(16))) unsigned short Bs[128 * 32];
    __shared__ float h1s[1024];
    __shared__ float wm_s[4], wl_s[4];
    int tid = threadIdx.x, bid = blockIdx.x;
    int lane = tid & 63, wid = tid >> 6;

    // LSTM pointwise (redundant per block); block 0 also writes h1/c1 outputs
    #pragma unroll
    for (int kk = 0; kk < 4; ++kk) {
        int j = tid + 256 * kk;
        float ig = gates[j], fg = gates[1024 + j], gg = gates[2048 + j], og = gates[3072 + j];
        float si = 1.f / (1.f + __expf(-ig));
        float sf = 1.f / (1.f + __expf(-fg));
        float so = 1.f / (1.f + __expf(-og));
        float c1 = sf * c0[j] + si * tanhf(gg);
        float h1 = so * tanhf(c1);
        h1s[j] = h1;
        if (bid == 0) { out[VS + j] = h1; out[VS + 1024 + j] = c1; }
    }
    __syncthreads();

    if (bid < 256) {
        // ---- GEMM tile: rows mbase..+64 (enc), cols nbase..+128 (Wc rows)
        int mbase = (bid >> 3) * 64;     // 32 m-tiles
        int nbase = (bid & 7) * 128;     // 8 n-tiles
        int wm = (wid >> 1) * 32;
        int wn = (wid & 1) * 64;
        int lrow = lane & 15;
        int lk = (lane >> 4) * 8;
        f32x4 acc[2][4] = {};
        for (int k0 = 0; k0 < 2048; k0 += 32) {
            {   // stage A 64x32 (1 chunk/thread)
                int row = tid >> 2, c8 = tid & 3;
                *(u16x8*)(As + row * 32 + c8 * 8) =
                    *(const u16x8*)(encb + (size_t)(mbase + row) * 2048 + k0 + c8 * 8);
            }
            #pragma unroll
            for (int p = 0; p < 2; ++p) {   // stage B 128x32 (2 chunks/thread)
                int fi = p * 256 + tid;
                int row = fi >> 2, c8 = fi & 3;
                *(u16x8*)(Bs + row * 32 + c8 * 8) =
                    *(const u16x8*)(Wcb + (size_t)(nbase + row) * 2048 + k0 + c8 * 8);
            }
            __syncthreads();
            bf16x8 af[2], bfr[4];
            #pragma unroll
            for (int t = 0; t < 2; ++t)
                af[t] = *(const bf16x8*)(As + (wm + t * 16 + lrow) * 32 + lk);
            #pragma unroll
            for (int t = 0; t < 4; ++t)
                bfr[t] = *(const bf16x8*)(Bs + (wn + t * 16 + lrow) * 32 + lk);
            #pragma unroll
            for (int mt = 0; mt < 2; ++mt)
                #pragma unroll
                for (int nt = 0; nt < 4; ++nt)
                    acc[mt][nt] = __builtin_amdgcn_mfma_f32_16x16x32_bf16(af[mt], bfr[nt], acc[mt][nt], 0, 0, 0);
            __syncthreads();
        }
        // ---- fused epilogue: scorec[row] += sum_cols tanh(acc + Wc_b)*h1
        int ccol = lane & 15;
        float bc[4], hc[4];
        #pragma unroll
        for (int nt = 0; nt < 4; ++nt) {
            int col = nbase + wn + nt * 16 + ccol;
            bc[nt] = Wc_b[col];
            hc[nt] = h1s[col];
        }
        #pragma unroll
        for (int mt = 0; mt < 2; ++mt)
            #pragma unroll
            for (int r = 0; r < 4; ++r) {
                float p = 0.f;
                #pragma unroll
                for (int nt = 0; nt < 4; ++nt)
                    p += tanhf(acc[mt][nt][r] + bc[nt]) * hc[nt];
                #pragma unroll
                for (int off = 1; off < 16; off <<= 1) p += __shfl_xor(p, off, 64);
                if ((lane & 15) == 0) {
                    int row = mbase + wm + mt * 16 + (lane >> 4) * 4 + r;
                    atomicAdd(&scorec[row], p);
                }
            }
        return;
    }

    // ---- Wo scoring path
    int wb = bid - 256;                  // 0..1791
    int gw = wb * 4 + wid;               // 0..7167
    float m = -1e30f, l = 0.f;
    const float4* hp = (const float4*)h1s;
    for (int v = gw; v < VV; v += NWOW) {
        const float4* rp = (const float4*)(Wo_W + (size_t)v * 1024);
        float acc = 0.f;
        #pragma unroll
        for (int k = 0; k < 4; ++k) {
            int idx = lane + 64 * k;
            float4 w = rp[idx]; float4 hv = hp[idx];
            acc += w.x*hv.x + w.y*hv.y + w.z*hv.z + w.w*hv.w;
        }
        acc = wave_reduce(acc);
        if (lane == 0) {
            float lg = acc + Wo_b[v];
            logits[v] = lg;
            float nm = fmaxf(m, lg);
            l = l * __expf(m - nm) + __expf(lg - nm);
            m = nm;
        }
    }
    if (lane == 0) { wm_s[wid] = m; wl_s[wid] = l; }
    __syncthreads();
    if (tid == 0) {
        float M = wm_s[0], L = wl_s[0];
        #pragma unroll
        for (int w = 1; w < 4; ++w) {
            float nm = fmaxf(M, wm_s[w]);
            L = L * __expf(M - nm) + wl_s[w] * __expf(wm_s[w] - nm);
            M = nm;
        }
        ms[wb] = M; ls[wb] = L;
    }
}

// ---- 6. k_final: merge 1792 Wo partials + redundant scorec fold, write probs
__global__ __launch_bounds__(256) void k_final(
        const float* __restrict__ ms, const float* __restrict__ ls,
        const float* __restrict__ scorec, const float* __restrict__ logits,
        float* __restrict__ out) {
    __shared__ float rm[256], rl[256];
    int tid = threadIdx.x;
    float m = -1e30f, l = 0.f;
    for (int i = tid; i < NWOB; i += 256) {
        float bm = ms[i], bl = ls[i];
        float nm = fmaxf(m, bm);
        l = l * __expf(m - nm) + bl * __expf(bm - nm);
        m = nm;
    }
    for (int i = tid; i < SS; i += 256) {
        float x = scorec[i];
        float nm = fmaxf(m, x);
        l = l * __expf(m - nm) + __expf(x - nm);
        m = nm;
    }
    rm[tid] = m; rl[tid] = l; __syncthreads();
    for (int o = 128; o > 0; o >>= 1) {
        if (tid < o) {
            float m2 = rm[tid + o], l2 = rl[tid + o];
            float nm = fmaxf(rm[tid], m2);
            rl[tid] = rl[tid] * __expf(rm[tid] - nm) + l2 * __expf(m2 - nm);
            rm[tid] = nm;
        }
        __syncthreads();
    }
    float M = rm[0], Linv = 1.f / rl[0];
    for (int v = blockIdx.x * 256 + tid; v < VS; v += 128 * 256) {
        float lg = (v < VV) ? logits[v] : scorec[v - VV];
        out[v] = __expf(lg - M) * Linv;
    }
}

extern "C" void kernel_launch(void* const* d_in, const int* in_sizes, int n_in,
                              void* d_out, int out_size, void* d_ws, size_t ws_size,
                              hipStream_t stream) {
    (void)in_sizes; (void)n_in; (void)out_size; (void)ws_size;
    const float* x          = (const float*)d_in[0];
    const float* enc        = (const float*)d_in[1];
    const int*   sentence   = (const int*)d_in[2];
    const float* prev_probs = (const float*)d_in[3];
    const float* h0         = (const float*)d_in[4];
    const float* c0         = (const float*)d_in[5];
    const float* attn_W     = (const float*)d_in[6];
    const float* attn_b     = (const float*)d_in[7];
    const float* comb_W     = (const float*)d_in[8];
    const float* comb_b     = (const float*)d_in[9];
    const float* Ws_W       = (const float*)d_in[10];
    const float* Ws_b       = (const float*)d_in[11];
    const float* Wo_W       = (const float*)d_in[12];
    const float* Wo_b       = (const float*)d_in[13];
    const float* Wc_W       = (const float*)d_in[14];
    const float* Wc_b       = (const float*)d_in[15];
    const float* W_ih       = (const float*)d_in[16];
    const float* W_hh       = (const float*)d_in[17];
    const float* b_ih       = (const float*)d_in[18];
    const float* b_hh       = (const float*)d_in[19];
    const int*   prev_word  = (const int*)d_in[20];
    float* ws  = (float*)d_ws;
    float* out = (float*)d_out;
    unsigned short* encb = (unsigned short*)(ws + OFF_ENCB);
    unsigned short* Wcb  = (unsigned short*)(ws + OFF_WCB);

    k_front<<<1282, 256, 0, stream>>>(x, h0, attn_W, attn_b, ws + OFF_LOGA,
                                      enc, Wc_W, encb, Wcb,
                                      ws + OFF_CTX, ws + OFF_LSTMIN);
    k_ctx<<<dim3(2, 32), 256, 0, stream>>>(enc, ws + OFF_LOGA, sentence, prev_probs,
                                           prev_word, ws + OFF_CTX, ws + OFF_SEL);
    k_comb<<<512, 256, 0, stream>>>(ws + OFF_CTX, ws + OFF_SEL, comb_W, comb_b,
                                    Ws_W, Ws_b, ws + OFF_LSTMIN);
    k_gates<<<1024, 256, 0, stream>>>(ws + OFF_LSTMIN, h0, W_ih, W_hh, b_ih, b_hh,
                                      ws + OFF_GATES);
    k_scores<<<2048, 256, 0, stream>>>(ws + OFF_GATES, c0, Wo_W, Wo_b, Wc_b,
                                       encb, Wcb, ws + OFF_LOG, out,
                                       ws + OFF_MS, ws + OFF_LS, ws + OFF_SCOREC);
    k_final<<<128, 256, 0, stream>>>(ws + OFF_MS, ws + OFF_LS, ws + OFF_SCOREC,
                                     ws + OFF_LOG, out);
}